// Round 4
// baseline (449.821 us; speedup 1.0000x reference)
//
#include <hip/hip_runtime.h>

typedef __bf16 bf16x8 __attribute__((ext_vector_type(8)));
typedef __bf16 bf16x2 __attribute__((ext_vector_type(2)));
typedef float  f32x4  __attribute__((ext_vector_type(4)));

// sizes: E=4 B=32 CI=64 H=W=64 CO=128 OH=OW=62
// ws layout: [0, 64MiB) features bf16 NHWC [eb][y][x][i]
//            [64MiB, +576KiB) weights bf16 [e][tap][j][i]
#define FT_BYTES 67108864ull

__device__ __forceinline__ void gl2lds16(const void* g, void* l) {
    __builtin_amdgcn_global_load_lds(
        (const __attribute__((address_space(1))) void*)g,
        (__attribute__((address_space(3))) void*)l, 16, 0, 0);
}

// prepass 1: weight fp32 [e][i][j][tap] -> bf16 [e][tap][j][i]
__global__ void wt_prep(const float* __restrict__ w, __bf16* __restrict__ wt) {
    int o = blockIdx.x * 256 + threadIdx.x;           // 294912 total
    int i = o & 63, j = (o >> 6) & 127, et = o >> 13; // et 0..35
    int tap = et % 9, e = et / 9;
    wt[o] = (__bf16)w[((e * 64 + i) * 128 + j) * 9 + tap];
}

// prepass 2: features fp32 NCHW -> bf16 NHWC, one block per (e,b,y)
__global__ void ft_prep(const float* __restrict__ f, __bf16* __restrict__ ft) {
    __shared__ float s[64 * 65];                      // [i][x], +1 pad
    int eb = blockIdx.z * 32 + blockIdx.y, y = blockIdx.x;
    const float* src = f + (size_t)eb * 262144 + y * 64;
    int t = threadIdx.x;
    for (int r = 0; r < 4; ++r) {
        int f4 = r * 256 + t;                         // 1024 float4
        int i = f4 >> 4, x4 = (f4 & 15) * 4;
        float4 v = *(const float4*)(src + i * 4096 + x4);
        s[i * 65 + x4 + 0] = v.x; s[i * 65 + x4 + 1] = v.y;
        s[i * 65 + x4 + 2] = v.z; s[i * 65 + x4 + 3] = v.w;
    }
    __syncthreads();
    bf16x2* dst = (bf16x2*)(ft + (size_t)(eb * 64 + y) * 4096);
    for (int r = 0; r < 8; ++r) {
        int q = r * 256 + t;                          // 2048 bf16x2; q = x*32+ih
        int x = q >> 5, ih = q & 31;
        bf16x2 pv;
        pv.x = (__bf16)s[(2 * ih + 0) * 65 + x];
        pv.y = (__bf16)s[(2 * ih + 1) * 65 + x];
        dst[q] = pv;
    }
}

// main: block = (y-pair, b-group of 16, e); 512 threads = 8 waves, 4M x 2N.
// Output tile per block: FULL j=128 x (2 rows x 64 px) per image.
//  - Weights: ALL 9 taps held in REGISTERS per wave (af[2][2][9], 144 VGPR),
//    loaded once per block from L2-resident wt, amortized over 16 images.
//    -> no sW in LDS, no j-split, features' L3 re-read factor halves.
//  - sF: 4 input rows (y0..y0+3) of current image, 32KB, double-buffered;
//    next image's stage issued before this image's compute (1 barrier/image).
//  - All 9 (A,Bt) tap shifts at LDS-read time (clamp feeds dead px>=62 only).
//  - Grid 31*2*4 = 248 blocks ~= one scheduling round (1 block/CU).
__global__ __launch_bounds__(512, 2)
void conv_main(const __bf16* __restrict__ ft, const __bf16* __restrict__ wt,
               const float* __restrict__ bias, float* __restrict__ out) {
    __shared__ __align__(16) __bf16 sF[2][16384];     // [R=y*64+x][i] 2x32KB
    const int y0 = blockIdx.x * 2, bg = blockIdx.y, e = blockIdx.z;
    const int t = threadIdx.x, lane = t & 63, w = t >> 6;
    const int wm = w >> 1, wn = w & 1;                // 4M x 2N waves
    const int q = lane >> 4, rm = lane & 15;

    // weights -> registers: j-row r = wm*32 + mi*16 + rm, k-chunk kh*4+q
    const __bf16* wbase = wt + ((size_t)(e * 9) << 13)
                        + (wm * 32 + rm) * 64 + q * 8;
    bf16x8 af[2][2][9];                               // [mi][kh][tap]
    #pragma unroll
    for (int tap = 0; tap < 9; ++tap)
        #pragma unroll
        for (int mi = 0; mi < 2; ++mi)
            #pragma unroll
            for (int kh = 0; kh < 2; ++kh)
                af[mi][kh][tap] =
                    *(const bf16x8*)(wbase + tap * 8192 + mi * 1024 + kh * 32);

    // stage image 0: 32 chunks of 1KB; 16B granule g at slot g^(r&7)
    const __bf16* fte = ft + ((size_t)(e * 32 + bg * 16) << 18)
                      + ((size_t)y0 << 12);
    for (int cc = 0; cc < 4; ++cc) {
        int c = w * 4 + cc;
        int r = c * 8 + (lane >> 3);                  // R-row 0..255
        int g = (lane & 7) ^ (r & 7);
        gl2lds16(fte + (r << 6) + g * 8, sF[0] + c * 512);
    }

    float bias_r[2][4];
    #pragma unroll
    for (int mi = 0; mi < 2; ++mi)
        #pragma unroll
        for (int vv = 0; vv < 4; ++vv)
            bias_r[mi][vv] = bias[e * 128 + wm * 32 + mi * 16 + q * 4 + vv];

    __syncthreads();                                  // af + sF[0] ready

    #pragma unroll 1
    for (int it = 0; it < 16; ++it) {
        const int buf = it & 1;
        const __bf16* sFb = sF[buf];
        if (it < 15) {                                // prefetch next image
            const __bf16* fn = fte + ((size_t)(it + 1) << 18);
            for (int cc = 0; cc < 4; ++cc) {
                int c = w * 4 + cc;
                int r = c * 8 + (lane >> 3);
                int g = (lane & 7) ^ (r & 7);
                gl2lds16(fn + (r << 6) + g * 8, sF[buf ^ 1] + c * 512);
            }
        }

        f32x4 acc[2][4] = {};
        #pragma unroll
        for (int tap = 0; tap < 9; ++tap) {
            const int A = tap / 3, Bt = tap - A * 3;
            #pragma unroll
            for (int kh = 0; kh < 2; ++kh) {
                const int kg = kh * 4;
                bf16x8 bq[4];
                #pragma unroll
                for (int ni = 0; ni < 4; ++ni) {
                    int p = wn * 64 + ni * 16 + rm;
                    int py = p >> 6, px = p & 63;
                    int xx = px + Bt; if (xx > 63) xx = 63;   // dead cols only
                    int r2 = (A + py) * 64 + xx;
                    int ch = (kg + q) ^ (r2 & 7);
                    bq[ni] = *(const bf16x8*)(sFb + r2 * 64 + ch * 8);
                }
                #pragma unroll
                for (int mi = 0; mi < 2; ++mi)
                    #pragma unroll
                    for (int ni = 0; ni < 4; ++ni)
                        acc[mi][ni] = __builtin_amdgcn_mfma_f32_16x16x32_bf16(
                            af[mi][kh][tap], bq[ni], acc[mi][ni], 0, 0, 0);
            }
        }

        // stores: D col(n=p)=lane&15, row(m=j)=(lane>>4)*4+reg
        const size_t eb = (size_t)(e * 32 + bg * 16 + it);
        for (int mi = 0; mi < 2; ++mi) {
            for (int ni = 0; ni < 4; ++ni) {
                int p = wn * 64 + ni * 16 + rm;
                int py = p >> 6, px = p & 63;
                if (px >= 62) continue;               // dead padding columns
                for (int vv = 0; vv < 4; ++vv) {
                    int j = wm * 32 + mi * 16 + q * 4 + vv;
                    float v = acc[mi][ni][vv] + bias_r[mi][vv];
                    out[((eb * 128 + j) * 62 + (y0 + py)) * 62 + px] = v;
                }
            }
        }
        if (it < 15) __syncthreads();                 // next buf staged + safe
    }
}

extern "C" void kernel_launch(void* const* d_in, const int* in_sizes, int n_in,
                              void* d_out, int out_size, void* d_ws, size_t ws_size,
                              hipStream_t stream) {
    const float* f    = (const float*)d_in[0];
    const float* wgt  = (const float*)d_in[1];
    const float* bias = (const float*)d_in[2];
    float* out = (float*)d_out;
    __bf16* ftw = (__bf16*)d_ws;
    __bf16* wtw = (__bf16*)((char*)d_ws + FT_BYTES);

    ft_prep<<<dim3(64, 32, 4), 256, 0, stream>>>(f, ftw);
    wt_prep<<<dim3(1152), 256, 0, stream>>>(wgt, wtw);
    conv_main<<<dim3(31, 2, 4), 512, 0, stream>>>(ftw, wtw, bias, out);
}